// Round 1
// baseline (745.818 us; speedup 1.0000x reference)
//
#include <hip/hip_runtime.h>
#include <cstdint>
#include <cstddef>

#define NUM_USERS 100000
#define NUM_ITEMS 100000
#define NUM_NODES 200000
#define NUM_EDGES 4000000
#define BATCH     4096
#define EMB       64

// ---------------- CSR build ----------------

__global__ void k_hist(const int* __restrict__ erow, int* __restrict__ counts) {
    int e = blockIdx.x * blockDim.x + threadIdx.x;
    if (e < NUM_EDGES) atomicAdd(&counts[erow[e]], 1);
}

#define SCAN_B 1024
__global__ void k_scan1(const int* __restrict__ counts, int* __restrict__ row_ptr,
                        int* __restrict__ bsums) {
    __shared__ int lds[SCAN_B];
    int t = threadIdx.x;
    int g = blockIdx.x * SCAN_B + t;
    int v = (g < NUM_NODES) ? counts[g] : 0;
    lds[t] = v;
    __syncthreads();
    for (int off = 1; off < SCAN_B; off <<= 1) {
        int add = (t >= off) ? lds[t - off] : 0;
        __syncthreads();
        lds[t] += add;
        __syncthreads();
    }
    if (g < NUM_NODES) row_ptr[g + 1] = lds[t];
    if (t == SCAN_B - 1) bsums[blockIdx.x] = lds[t];
}

__global__ void k_scan2(int* __restrict__ bsums, int nb) {
    if (threadIdx.x == 0 && blockIdx.x == 0) {
        int run = 0;
        for (int i = 0; i < nb; ++i) { int t = bsums[i]; bsums[i] = run; run += t; }
    }
}

__global__ void k_scan3(int* __restrict__ row_ptr, const int* __restrict__ bsums) {
    int g = blockIdx.x * SCAN_B + threadIdx.x;
    if (g < NUM_NODES) row_ptr[g + 1] += bsums[blockIdx.x];
    if (g == 0) row_ptr[0] = 0;
}

__global__ void k_scatter(const int* __restrict__ erow, const int* __restrict__ ecol,
                          const float* __restrict__ eval_, int* __restrict__ cursor,
                          int* __restrict__ scol, float* __restrict__ sval) {
    int e = blockIdx.x * blockDim.x + threadIdx.x;
    if (e < NUM_EDGES) {
        int r = erow[e];
        int p = atomicAdd(&cursor[r], 1);
        scol[p] = ecol[e];
        sval[p] = eval_[e];
    }
}

// ---------------- SpMM layer 1: h1 = A * x  (wave per row, lane = dim) ----------------

__device__ __forceinline__ const float* node_ptr(int c, const float* __restrict__ uemb,
                                                 const float* __restrict__ iemb) {
    return (c < NUM_USERS) ? (uemb + (size_t)c * EMB)
                           : (iemb + (size_t)(c - NUM_USERS) * EMB);
}

__global__ void k_spmm1(const int* __restrict__ row_ptr, const int* __restrict__ scol,
                        const float* __restrict__ sval,
                        const float* __restrict__ uemb, const float* __restrict__ iemb,
                        float* __restrict__ h1) {
    int wid  = (blockIdx.x * blockDim.x + threadIdx.x) >> 6;
    int lane = threadIdx.x & 63;
    if (wid >= NUM_NODES) return;
    int s = row_ptr[wid];
    int t = row_ptr[wid + 1];
    float acc = 0.f;
    int e = s;
    for (; e + 4 <= t; e += 4) {
        int   c0 = scol[e],     c1 = scol[e + 1], c2 = scol[e + 2], c3 = scol[e + 3];
        float v0 = sval[e],     v1 = sval[e + 1], v2 = sval[e + 2], v3 = sval[e + 3];
        const float* p0 = node_ptr(c0, uemb, iemb);
        const float* p1 = node_ptr(c1, uemb, iemb);
        const float* p2 = node_ptr(c2, uemb, iemb);
        const float* p3 = node_ptr(c3, uemb, iemb);
        float x0 = p0[lane], x1 = p1[lane], x2 = p2[lane], x3 = p3[lane];
        acc = fmaf(v0, x0, acc);
        acc = fmaf(v1, x1, acc);
        acc = fmaf(v2, x2, acc);
        acc = fmaf(v3, x3, acc);
    }
    for (; e < t; ++e) {
        int c = scol[e];
        float v = sval[e];
        acc = fmaf(v, node_ptr(c, uemb, iemb)[lane], acc);
    }
    h1[(size_t)wid * EMB + lane] = acc;
}

// ---------------- Fused layer 2 + scoring ----------------
// block = 192 threads = 3 waves: wave0 -> user row, wave1 -> pos row, wave2 -> neg row.
// acc = (x + h1 + A*h1)[node] / 3 ; then pos/neg dot products via wave reduction.

__global__ void k_final(const int* __restrict__ user, const int* __restrict__ pos,
                        const int* __restrict__ neg,
                        const int* __restrict__ row_ptr, const int* __restrict__ scol,
                        const float* __restrict__ sval,
                        const float* __restrict__ uemb, const float* __restrict__ iemb,
                        const float* __restrict__ h1, float* __restrict__ out) {
    __shared__ float lds[3 * EMB];
    int b    = blockIdx.x;
    int w    = threadIdx.x >> 6;
    int lane = threadIdx.x & 63;

    int node;
    if (w == 0)      node = user[b];
    else if (w == 1) node = NUM_USERS + pos[b];
    else             node = NUM_USERS + neg[b];

    const float* xb = node_ptr(node, uemb, iemb);
    float acc = xb[lane] + h1[(size_t)node * EMB + lane];

    int s = row_ptr[node];
    int t = row_ptr[node + 1];
    int e = s;
    for (; e + 2 <= t; e += 2) {
        int   c0 = scol[e],  c1 = scol[e + 1];
        float v0 = sval[e],  v1 = sval[e + 1];
        float y0 = h1[(size_t)c0 * EMB + lane];
        float y1 = h1[(size_t)c1 * EMB + lane];
        acc = fmaf(v0, y0, acc);
        acc = fmaf(v1, y1, acc);
    }
    for (; e < t; ++e)
        acc = fmaf(sval[e], h1[(size_t)scol[e] * EMB + lane], acc);

    acc = acc / 3.0f;
    lds[w * EMB + lane] = acc;
    __syncthreads();

    if (w < 2) {
        float prod = lds[lane] * lds[(w + 1) * EMB + lane];
        for (int off = 32; off; off >>= 1) prod += __shfl_xor(prod, off, 64);
        if (lane == 0) out[w * BATCH + b] = prod;
    }
}

// ---------------- launch ----------------

extern "C" void kernel_launch(void* const* d_in, const int* in_sizes, int n_in,
                              void* d_out, int out_size, void* d_ws, size_t ws_size,
                              hipStream_t stream) {
    const int*   user  = (const int*)d_in[0];
    const int*   pos   = (const int*)d_in[1];
    const int*   neg   = (const int*)d_in[2];
    const int*   erow  = (const int*)d_in[3];
    const int*   ecol  = (const int*)d_in[4];
    const float* eval_ = (const float*)d_in[5];
    const float* uemb  = (const float*)d_in[6];
    const float* iemb  = (const float*)d_in[7];
    float* out = (float*)d_out;

    char* ws = (char*)d_ws;
    // layout (bytes):
    //   h1      : 0          .. 51,200,000   (200000*64 f32)
    //   counts  : 51,200,000 .. +800,256
    //   row_ptr : 52,000,256 .. +800,256     (200001 ints)
    //   cursor  : 52,800,512 .. +800,256
    //   bsums   : 53,600,768 .. +4,096
    //   scol    : 53,604,864 .. +16,000,000
    //   sval    : 69,604,864 .. +16,000,000  (end 85,604,864)
    float* h1      = (float*)(ws);
    int*   counts  = (int*)(ws + 51200000);
    int*   row_ptr = (int*)(ws + 52000256);
    int*   cursor  = (int*)(ws + 52800512);
    int*   bsums   = (int*)(ws + 53600768);
    int*   scol    = (int*)(ws + 53604864);
    float* sval    = (float*)(ws + 69604864);

    hipMemsetAsync(counts, 0, NUM_NODES * sizeof(int), stream);

    k_hist<<<(NUM_EDGES + 255) / 256, 256, 0, stream>>>(erow, counts);

    int nb = (NUM_NODES + SCAN_B - 1) / SCAN_B;  // 196
    k_scan1<<<nb, SCAN_B, 0, stream>>>(counts, row_ptr, bsums);
    k_scan2<<<1, 64, 0, stream>>>(bsums, nb);
    k_scan3<<<nb, SCAN_B, 0, stream>>>(row_ptr, bsums);

    hipMemcpyAsync(cursor, row_ptr, NUM_NODES * sizeof(int),
                   hipMemcpyDeviceToDevice, stream);

    k_scatter<<<(NUM_EDGES + 255) / 256, 256, 0, stream>>>(erow, ecol, eval_,
                                                           cursor, scol, sval);

    k_spmm1<<<(NUM_NODES * 64 + 255) / 256, 256, 0, stream>>>(row_ptr, scol, sval,
                                                              uemb, iemb, h1);

    k_final<<<BATCH, 192, 0, stream>>>(user, pos, neg, row_ptr, scol, sval,
                                       uemb, iemb, h1, out);
}

// Round 3
// 709.076 us; speedup vs baseline: 1.0518x; 1.0518x over previous
//
#include <hip/hip_runtime.h>
#include <cstdint>
#include <cstddef>

#define NUM_USERS 100000
#define NUM_ITEMS 100000
#define NUM_NODES 200000
#define NUM_EDGES 4000000
#define BATCH     4096
#define EMB       64

// ---------------- CSR build ----------------

__global__ void k_hist(const int* __restrict__ erow, int* __restrict__ counts) {
    int i = blockIdx.x * blockDim.x + threadIdx.x;
    int e = i * 2;
    if (e + 1 < NUM_EDGES) {
        int2 r = *(const int2*)(erow + e);
        atomicAdd(&counts[r.x], 1);
        atomicAdd(&counts[r.y], 1);
    } else if (e < NUM_EDGES) {
        atomicAdd(&counts[erow[e]], 1);
    }
}

#define SCAN_B 1024
__global__ void k_scan1(const int* __restrict__ counts, int* __restrict__ row_ptr,
                        int* __restrict__ bsums) {
    __shared__ int lds[SCAN_B];
    int t = threadIdx.x;
    int g = blockIdx.x * SCAN_B + t;
    int v = (g < NUM_NODES) ? counts[g] : 0;
    lds[t] = v;
    __syncthreads();
    for (int off = 1; off < SCAN_B; off <<= 1) {
        int add = (t >= off) ? lds[t - off] : 0;
        __syncthreads();
        lds[t] += add;
        __syncthreads();
    }
    if (g < NUM_NODES) row_ptr[g + 1] = lds[t];
    if (t == SCAN_B - 1) bsums[blockIdx.x] = lds[t];
}

__global__ void k_scan2(int* __restrict__ bsums, int nb) {
    if (threadIdx.x == 0 && blockIdx.x == 0) {
        int run = 0;
        for (int i = 0; i < nb; ++i) { int t = bsums[i]; bsums[i] = run; run += t; }
    }
}

__global__ void k_scan3(int* __restrict__ row_ptr, const int* __restrict__ bsums) {
    int g = blockIdx.x * SCAN_B + threadIdx.x;
    if (g < NUM_NODES) row_ptr[g + 1] += bsums[blockIdx.x];
    if (g == 0) row_ptr[0] = 0;
}

// Packed scatter: one 8-byte record per edge -> one dirty cache line per edge
// instead of two (scol + sval separately).
__global__ void k_scatter(const int* __restrict__ erow, const int* __restrict__ ecol,
                          const float* __restrict__ eval_, int* __restrict__ cursor,
                          int2* __restrict__ epack) {
    int e = blockIdx.x * blockDim.x + threadIdx.x;
    if (e < NUM_EDGES) {
        int r = erow[e];
        int p = atomicAdd(&cursor[r], 1);
        epack[p] = make_int2(ecol[e], __float_as_int(eval_[e]));
    }
}

// ---------------- SpMM layer 1: h1 = A * x  (wave per row, lane = dim) ----------------

__device__ __forceinline__ const float* node_ptr(int c, const float* __restrict__ uemb,
                                                 const float* __restrict__ iemb) {
    return (c < NUM_USERS) ? (uemb + (size_t)c * EMB)
                           : (iemb + (size_t)(c - NUM_USERS) * EMB);
}

__global__ void k_spmm1(const int* __restrict__ row_ptr, const int2* __restrict__ epack,
                        const float* __restrict__ uemb, const float* __restrict__ iemb,
                        float* __restrict__ h1) {
    int wid  = (blockIdx.x * blockDim.x + threadIdx.x) >> 6;
    int lane = threadIdx.x & 63;
    if (wid >= NUM_NODES) return;
    int s = row_ptr[wid];
    int t = row_ptr[wid + 1];
    float acc0 = 0.f, acc1 = 0.f;
    int e = s;
    for (; e + 4 <= t; e += 4) {
        int2 p0 = epack[e],     p1 = epack[e + 1];
        int2 p2 = epack[e + 2], p3 = epack[e + 3];
        const float* q0 = node_ptr(p0.x, uemb, iemb);
        const float* q1 = node_ptr(p1.x, uemb, iemb);
        const float* q2 = node_ptr(p2.x, uemb, iemb);
        const float* q3 = node_ptr(p3.x, uemb, iemb);
        float x0 = q0[lane], x1 = q1[lane], x2 = q2[lane], x3 = q3[lane];
        acc0 = fmaf(__int_as_float(p0.y), x0, acc0);
        acc1 = fmaf(__int_as_float(p1.y), x1, acc1);
        acc0 = fmaf(__int_as_float(p2.y), x2, acc0);
        acc1 = fmaf(__int_as_float(p3.y), x3, acc1);
    }
    for (; e < t; ++e) {
        int2 p = epack[e];
        acc0 = fmaf(__int_as_float(p.y), node_ptr(p.x, uemb, iemb)[lane], acc0);
    }
    h1[(size_t)wid * EMB + lane] = acc0 + acc1;
}

// ---------------- Fused layer 2 + scoring ----------------
// block = 192 threads = 3 waves: wave0 -> user row, wave1 -> pos row, wave2 -> neg row.
// acc = (x + h1 + A*h1)[node] / 3 ; then pos/neg dot products via wave reduction.

__global__ void k_final(const int* __restrict__ user, const int* __restrict__ pos,
                        const int* __restrict__ neg,
                        const int* __restrict__ row_ptr, const int2* __restrict__ epack,
                        const float* __restrict__ uemb, const float* __restrict__ iemb,
                        const float* __restrict__ h1, float* __restrict__ out) {
    __shared__ float lds[3 * EMB];
    int b    = blockIdx.x;
    int w    = threadIdx.x >> 6;
    int lane = threadIdx.x & 63;

    int node;
    if (w == 0)      node = user[b];
    else if (w == 1) node = NUM_USERS + pos[b];
    else             node = NUM_USERS + neg[b];

    const float* xb = node_ptr(node, uemb, iemb);
    float acc = xb[lane] + h1[(size_t)node * EMB + lane];

    int s = row_ptr[node];
    int t = row_ptr[node + 1];
    int e = s;
    for (; e + 2 <= t; e += 2) {
        int2 p0 = epack[e], p1 = epack[e + 1];
        float y0 = h1[(size_t)p0.x * EMB + lane];
        float y1 = h1[(size_t)p1.x * EMB + lane];
        acc = fmaf(__int_as_float(p0.y), y0, acc);
        acc = fmaf(__int_as_float(p1.y), y1, acc);
    }
    for (; e < t; ++e) {
        int2 p = epack[e];
        acc = fmaf(__int_as_float(p.y), h1[(size_t)p.x * EMB + lane], acc);
    }

    acc = acc / 3.0f;
    lds[w * EMB + lane] = acc;
    __syncthreads();

    if (w < 2) {
        float prod = lds[lane] * lds[(w + 1) * EMB + lane];
        for (int off = 32; off; off >>= 1) prod += __shfl_xor(prod, off, 64);
        if (lane == 0) out[w * BATCH + b] = prod;
    }
}

// ---------------- launch ----------------

extern "C" void kernel_launch(void* const* d_in, const int* in_sizes, int n_in,
                              void* d_out, int out_size, void* d_ws, size_t ws_size,
                              hipStream_t stream) {
    const int*   user  = (const int*)d_in[0];
    const int*   pos   = (const int*)d_in[1];
    const int*   neg   = (const int*)d_in[2];
    const int*   erow  = (const int*)d_in[3];
    const int*   ecol  = (const int*)d_in[4];
    const float* eval_ = (const float*)d_in[5];
    const float* uemb  = (const float*)d_in[6];
    const float* iemb  = (const float*)d_in[7];
    float* out = (float*)d_out;

    char* ws = (char*)d_ws;
    // layout (bytes):
    //   h1      : 0          .. 51,200,000   (200000*64 f32)
    //   counts  : 51,200,000 .. +800,256
    //   row_ptr : 52,000,256 .. +800,256     (200001 ints)
    //   cursor  : 52,800,512 .. +800,256
    //   bsums   : 53,600,768 .. +4,096
    //   epack   : 53,604,864 .. +32,000,000  (end 85,604,864)
    float* h1      = (float*)(ws);
    int*   counts  = (int*)(ws + 51200000);
    int*   row_ptr = (int*)(ws + 52000256);
    int*   cursor  = (int*)(ws + 52800512);
    int*   bsums   = (int*)(ws + 53600768);
    int2*  epack   = (int2*)(ws + 53604864);

    hipMemsetAsync(counts, 0, NUM_NODES * sizeof(int), stream);

    k_hist<<<(NUM_EDGES / 2 + 255) / 256, 256, 0, stream>>>(erow, counts);

    int nb = (NUM_NODES + SCAN_B - 1) / SCAN_B;  // 196
    k_scan1<<<nb, SCAN_B, 0, stream>>>(counts, row_ptr, bsums);
    k_scan2<<<1, 64, 0, stream>>>(bsums, nb);
    k_scan3<<<nb, SCAN_B, 0, stream>>>(row_ptr, bsums);

    hipMemcpyAsync(cursor, row_ptr, NUM_NODES * sizeof(int),
                   hipMemcpyDeviceToDevice, stream);

    k_scatter<<<(NUM_EDGES + 255) / 256, 256, 0, stream>>>(erow, ecol, eval_,
                                                           cursor, epack);

    k_spmm1<<<(NUM_NODES * 64 + 255) / 256, 256, 0, stream>>>(row_ptr, epack,
                                                              uemb, iemb, h1);

    k_final<<<BATCH, 192, 0, stream>>>(user, pos, neg, row_ptr, epack,
                                       uemb, iemb, h1, out);
}

// Round 4
// 618.498 us; speedup vs baseline: 1.2059x; 1.1464x over previous
//
#include <hip/hip_runtime.h>
#include <cstdint>
#include <cstddef>

#define NUM_USERS 100000
#define NUM_ITEMS 100000
#define NUM_NODES 200000
#define NUM_EDGES 4000000
#define BATCH     4096
#define EMB       64

#define NB    782          // ceil(NUM_NODES / 256) buckets (bucket = row >> 8)
#define CHUNK 8192         // edges per block in k_part1
#define EPB   32           // CHUNK / 256 edges per thread

// ---------------- per-row histogram ----------------

__global__ void k_hist(const int* __restrict__ erow, int* __restrict__ counts) {
    int i = blockIdx.x * blockDim.x + threadIdx.x;
    int e = i * 2;
    if (e + 1 < NUM_EDGES) {
        int2 r = *(const int2*)(erow + e);
        atomicAdd(&counts[r.x], 1);
        atomicAdd(&counts[r.y], 1);
    } else if (e < NUM_EDGES) {
        atomicAdd(&counts[erow[e]], 1);
    }
}

#define SCAN_B 1024
__global__ void k_scan1(const int* __restrict__ counts, int* __restrict__ row_ptr,
                        int* __restrict__ bsums) {
    __shared__ int lds[SCAN_B];
    int t = threadIdx.x;
    int g = blockIdx.x * SCAN_B + t;
    int v = (g < NUM_NODES) ? counts[g] : 0;
    lds[t] = v;
    __syncthreads();
    for (int off = 1; off < SCAN_B; off <<= 1) {
        int add = (t >= off) ? lds[t - off] : 0;
        __syncthreads();
        lds[t] += add;
        __syncthreads();
    }
    if (g < NUM_NODES) row_ptr[g + 1] = lds[t];
    if (t == SCAN_B - 1) bsums[blockIdx.x] = lds[t];
}

__global__ void k_scan2(int* __restrict__ bsums, int nb) {
    if (threadIdx.x == 0 && blockIdx.x == 0) {
        int run = 0;
        for (int i = 0; i < nb; ++i) { int t = bsums[i]; bsums[i] = run; run += t; }
    }
}

__global__ void k_scan3(int* __restrict__ row_ptr, const int* __restrict__ bsums) {
    int g = blockIdx.x * SCAN_B + threadIdx.x;
    if (g < NUM_NODES) row_ptr[g + 1] += bsums[blockIdx.x];
    if (g == 0) row_ptr[0] = 0;
}

// ---------------- two-level partition ----------------

__global__ void k_binit(const int* __restrict__ row_ptr, int* __restrict__ bcur) {
    int b = blockIdx.x * blockDim.x + threadIdx.x;
    if (b < NB) bcur[b] = row_ptr[b << 8];
}

// Pass 1: partition edges into 782 row-buckets. Per-block LDS histogram ->
// one global atomic per (block,bucket); per-(block,bucket) writes contiguous
// (~2 lines each) -> ~1.5x write amplification instead of 8x.
__global__ void k_part1(const int* __restrict__ erow, const int* __restrict__ ecol,
                        const float* __restrict__ eval_, int* __restrict__ bcur,
                        int2* __restrict__ tmp) {
    __shared__ int hist[NB];
    __shared__ int base[NB];
    int t = threadIdx.x;
    int start = blockIdx.x * CHUNK;
    for (int i = t; i < NB; i += 256) hist[i] = 0;
    __syncthreads();
    int rows[EPB], ranks[EPB];
#pragma unroll
    for (int k = 0; k < EPB; ++k) {
        int e = start + t + k * 256;
        if (e < NUM_EDGES) {
            int r = erow[e];
            rows[k]  = r;
            ranks[k] = atomicAdd(&hist[r >> 8], 1);
        } else {
            rows[k] = -1;
        }
    }
    __syncthreads();
    for (int i = t; i < NB; i += 256) {
        int c = hist[i];
        base[i] = c ? atomicAdd(&bcur[i], c) : 0;
    }
    __syncthreads();
#pragma unroll
    for (int k = 0; k < EPB; ++k) {
        int e = start + t + k * 256;
        if (rows[k] >= 0) {
            int r   = rows[k];
            int pos = base[r >> 8] + ranks[k];
            tmp[pos] = make_int2(((r & 255) << 24) | ecol[e], __float_as_int(eval_[e]));
        }
    }
}

// Pass 2: exact CSR scatter inside each ~40 KB bucket window. All cursors in
// LDS (zero global atomics); random writes confined to the window -> L2
// absorbs and merges lines.
__global__ void k_part2(const int* __restrict__ row_ptr, const int2* __restrict__ tmp,
                        int2* __restrict__ epack) {
    __shared__ int lcur[256];
    int b = blockIdx.x, t = threadIdx.x;
    int base_row = b << 8;
    int nrows = min(256, NUM_NODES - base_row);
    if (t < nrows) lcur[t] = row_ptr[base_row + t];
    __syncthreads();
    int s   = row_ptr[base_row];
    int end = row_ptr[base_row + nrows];
    for (int i = s + t; i < end; i += 256) {
        int2 rec  = tmp[i];
        int rowoff = ((unsigned)rec.x) >> 24;
        int pos = atomicAdd(&lcur[rowoff], 1);
        epack[pos] = make_int2(rec.x & 0xFFFFFF, rec.y);
    }
}

// ---------------- legacy one-shot scatter (ws-size fallback) ----------------

__global__ void k_scatter(const int* __restrict__ erow, const int* __restrict__ ecol,
                          const float* __restrict__ eval_, int* __restrict__ cursor,
                          int2* __restrict__ epack) {
    int e = blockIdx.x * blockDim.x + threadIdx.x;
    if (e < NUM_EDGES) {
        int r = erow[e];
        int p = atomicAdd(&cursor[r], 1);
        epack[p] = make_int2(ecol[e], __float_as_int(eval_[e]));
    }
}

// ---------------- SpMM layer 1: h1 = A * x  (wave per row, lane = dim) ----------------

__device__ __forceinline__ const float* node_ptr(int c, const float* __restrict__ uemb,
                                                 const float* __restrict__ iemb) {
    return (c < NUM_USERS) ? (uemb + (size_t)c * EMB)
                           : (iemb + (size_t)(c - NUM_USERS) * EMB);
}

__global__ void k_spmm1(const int* __restrict__ row_ptr, const int2* __restrict__ epack,
                        const float* __restrict__ uemb, const float* __restrict__ iemb,
                        float* __restrict__ h1) {
    int wid  = (blockIdx.x * blockDim.x + threadIdx.x) >> 6;
    int lane = threadIdx.x & 63;
    if (wid >= NUM_NODES) return;
    int s = row_ptr[wid];
    int t = row_ptr[wid + 1];
    float acc0 = 0.f, acc1 = 0.f;
    int e = s;
    for (; e + 4 <= t; e += 4) {
        int2 p0 = epack[e],     p1 = epack[e + 1];
        int2 p2 = epack[e + 2], p3 = epack[e + 3];
        const float* q0 = node_ptr(p0.x, uemb, iemb);
        const float* q1 = node_ptr(p1.x, uemb, iemb);
        const float* q2 = node_ptr(p2.x, uemb, iemb);
        const float* q3 = node_ptr(p3.x, uemb, iemb);
        float x0 = q0[lane], x1 = q1[lane], x2 = q2[lane], x3 = q3[lane];
        acc0 = fmaf(__int_as_float(p0.y), x0, acc0);
        acc1 = fmaf(__int_as_float(p1.y), x1, acc1);
        acc0 = fmaf(__int_as_float(p2.y), x2, acc0);
        acc1 = fmaf(__int_as_float(p3.y), x3, acc1);
    }
    for (; e < t; ++e) {
        int2 p = epack[e];
        acc0 = fmaf(__int_as_float(p.y), node_ptr(p.x, uemb, iemb)[lane], acc0);
    }
    h1[(size_t)wid * EMB + lane] = acc0 + acc1;
}

// ---------------- Fused layer 2 + scoring ----------------

__global__ void k_final(const int* __restrict__ user, const int* __restrict__ pos,
                        const int* __restrict__ neg,
                        const int* __restrict__ row_ptr, const int2* __restrict__ epack,
                        const float* __restrict__ uemb, const float* __restrict__ iemb,
                        const float* __restrict__ h1, float* __restrict__ out) {
    __shared__ float lds[3 * EMB];
    int b    = blockIdx.x;
    int w    = threadIdx.x >> 6;
    int lane = threadIdx.x & 63;

    int node;
    if (w == 0)      node = user[b];
    else if (w == 1) node = NUM_USERS + pos[b];
    else             node = NUM_USERS + neg[b];

    const float* xb = node_ptr(node, uemb, iemb);
    float acc = xb[lane] + h1[(size_t)node * EMB + lane];

    int s = row_ptr[node];
    int t = row_ptr[node + 1];
    int e = s;
    for (; e + 2 <= t; e += 2) {
        int2 p0 = epack[e], p1 = epack[e + 1];
        float y0 = h1[(size_t)p0.x * EMB + lane];
        float y1 = h1[(size_t)p1.x * EMB + lane];
        acc = fmaf(__int_as_float(p0.y), y0, acc);
        acc = fmaf(__int_as_float(p1.y), y1, acc);
    }
    for (; e < t; ++e) {
        int2 p = epack[e];
        acc = fmaf(__int_as_float(p.y), h1[(size_t)p.x * EMB + lane], acc);
    }

    acc = acc / 3.0f;
    lds[w * EMB + lane] = acc;
    __syncthreads();

    if (w < 2) {
        float prod = lds[lane] * lds[(w + 1) * EMB + lane];
        for (int off = 32; off; off >>= 1) prod += __shfl_xor(prod, off, 64);
        if (lane == 0) out[w * BATCH + b] = prod;
    }
}

// ---------------- launch ----------------

extern "C" void kernel_launch(void* const* d_in, const int* in_sizes, int n_in,
                              void* d_out, int out_size, void* d_ws, size_t ws_size,
                              hipStream_t stream) {
    const int*   user  = (const int*)d_in[0];
    const int*   pos   = (const int*)d_in[1];
    const int*   neg   = (const int*)d_in[2];
    const int*   erow  = (const int*)d_in[3];
    const int*   ecol  = (const int*)d_in[4];
    const float* eval_ = (const float*)d_in[5];
    const float* uemb  = (const float*)d_in[6];
    const float* iemb  = (const float*)d_in[7];
    float* out = (float*)d_out;

    char* ws = (char*)d_ws;
    // layout (bytes):
    //   h1      : 0          .. 51,200,000   (200000*64 f32)
    //   counts  : 51,200,000 .. +800,256
    //   row_ptr : 52,000,256 .. +800,256     (200001 ints)
    //   bsums   : 52,800,512 .. +4,096
    //   bcur    : 52,804,608 .. +4,096      (782 ints; doubles as cursor base in fallback)
    //   epack   : 52,808,704 .. +32,000,000 (end 84,808,704)
    //   tmp     : 84,808,704 .. +32,000,000 (end 116,808,704) [two-pass path only]
    float* h1      = (float*)(ws);
    int*   counts  = (int*)(ws + 51200000);
    int*   row_ptr = (int*)(ws + 52000256);
    int*   bsums   = (int*)(ws + 52800512);
    int*   bcur    = (int*)(ws + 52804608);
    int2*  epack   = (int2*)(ws + 52808704);
    int2*  tmp     = (int2*)(ws + 84808704);

    hipMemsetAsync(counts, 0, NUM_NODES * sizeof(int), stream);

    k_hist<<<(NUM_EDGES / 2 + 255) / 256, 256, 0, stream>>>(erow, counts);

    int nb = (NUM_NODES + SCAN_B - 1) / SCAN_B;  // 196
    k_scan1<<<nb, SCAN_B, 0, stream>>>(counts, row_ptr, bsums);
    k_scan2<<<1, 64, 0, stream>>>(bsums, nb);
    k_scan3<<<nb, SCAN_B, 0, stream>>>(row_ptr, bsums);

    if (ws_size >= 116808704ull) {
        // two-level partition: bucket scatter (coalesced-ish) + in-window CSR scatter
        k_binit<<<(NB + 255) / 256, 256, 0, stream>>>(row_ptr, bcur);
        k_part1<<<(NUM_EDGES + CHUNK - 1) / CHUNK, 256, 0, stream>>>(erow, ecol, eval_,
                                                                     bcur, tmp);
        k_part2<<<NB, 256, 0, stream>>>(row_ptr, tmp, epack);
    } else {
        // fallback: legacy direct scatter (needs cursor = copy of row_ptr)
        // reuse counts region as cursor
        hipMemcpyAsync(counts, row_ptr, NUM_NODES * sizeof(int),
                       hipMemcpyDeviceToDevice, stream);
        k_scatter<<<(NUM_EDGES + 255) / 256, 256, 0, stream>>>(erow, ecol, eval_,
                                                               counts, epack);
    }

    k_spmm1<<<(NUM_NODES * 64 + 255) / 256, 256, 0, stream>>>(row_ptr, epack,
                                                              uemb, iemb, h1);

    k_final<<<BATCH, 192, 0, stream>>>(user, pos, neg, row_ptr, epack,
                                       uemb, iemb, h1, out);
}

// Round 5
// 460.355 us; speedup vs baseline: 1.6201x; 1.3435x over previous
//
#include <hip/hip_runtime.h>
#include <cstdint>
#include <cstddef>

#define NUM_USERS 100000
#define NUM_ITEMS 100000
#define NUM_NODES 200000
#define NUM_EDGES 4000000
#define BATCH     4096
#define EMB       64

#define NB    782          // ceil(NUM_NODES / 256) buckets (bucket = row >> 8)
#define CHUNK 8192         // edges per block in k_bhist / k_part1
#define EPB   32           // CHUNK / 256 edges per thread

// ---------------- bf16 helpers (round-to-nearest-even) ----------------

__device__ __forceinline__ unsigned short f2bf(float f) {
    unsigned u = __float_as_uint(f);
    u = (u + 0x7FFFu + ((u >> 16) & 1u)) >> 16;
    return (unsigned short)u;
}
__device__ __forceinline__ float bf2f(unsigned short b) {
    return __uint_as_float(((unsigned)b) << 16);
}

// ---------------- convert fp32 embeddings -> bf16 table (user ‖ item) ----------------

__global__ void k_cvt(const float* __restrict__ uemb, const float* __restrict__ iemb,
                      unsigned short* __restrict__ xb) {
    int i = blockIdx.x * blockDim.x + threadIdx.x;           // 8 elems / thread
    const int TOT8 = (NUM_NODES * EMB) / 8;                  // 1.6M
    if (i >= TOT8) return;
    size_t off = (size_t)i * 8;
    const size_t UELEMS = (size_t)NUM_USERS * EMB;           // divisible by 8
    const float* src = (off < UELEMS) ? (uemb + off) : (iemb + (off - UELEMS));
    float4 f0 = ((const float4*)src)[0];
    float4 f1 = ((const float4*)src)[1];
    ushort4 o0 = make_ushort4(f2bf(f0.x), f2bf(f0.y), f2bf(f0.z), f2bf(f0.w));
    ushort4 o1 = make_ushort4(f2bf(f1.x), f2bf(f1.y), f2bf(f1.z), f2bf(f1.w));
    ((ushort4*)(xb + off))[0] = o0;
    ((ushort4*)(xb + off))[1] = o1;
}

// ---------------- bucket histogram (782 buckets, LDS-aggregated) ----------------

__global__ void k_bhist(const int* __restrict__ erow, int* __restrict__ bcnt) {
    __shared__ int h[NB];
    int t = threadIdx.x;
    int start = blockIdx.x * CHUNK;
    for (int i = t; i < NB; i += 256) h[i] = 0;
    __syncthreads();
#pragma unroll
    for (int k = 0; k < EPB; ++k) {
        int e = start + t + k * 256;
        if (e < NUM_EDGES) atomicAdd(&h[erow[e] >> 8], 1);
    }
    __syncthreads();
    for (int i = t; i < NB; i += 256) {
        int c = h[i];
        if (c) atomicAdd(&bcnt[i], c);
    }
}

// exclusive scan over 782 bucket counts -> bbase[0..NB], init bcur
__global__ void k_bscan(const int* __restrict__ bcnt, int* __restrict__ bbase,
                        int* __restrict__ bcur) {
    __shared__ int lds[1024];
    int t = threadIdx.x;
    int v = (t < NB) ? bcnt[t] : 0;
    lds[t] = v;
    __syncthreads();
    for (int off = 1; off < 1024; off <<= 1) {
        int add = (t >= off) ? lds[t - off] : 0;
        __syncthreads();
        lds[t] += add;
        __syncthreads();
    }
    int ex = lds[t] - v;
    if (t < NB) { bbase[t] = ex; bcur[t] = ex; }
    if (t == NB - 1) bbase[NB] = lds[t];
}

// ---------------- two-level partition ----------------

// Pass 1: partition edges into 782 row-buckets of tmp. Per-block LDS histogram
// -> one global atomic per (block,bucket); per-(block,bucket) writes contiguous.
__global__ void k_part1(const int* __restrict__ erow, const int* __restrict__ ecol,
                        const float* __restrict__ eval_, int* __restrict__ bcur,
                        int2* __restrict__ tmp) {
    __shared__ int hist[NB];
    __shared__ int base[NB];
    int t = threadIdx.x;
    int start = blockIdx.x * CHUNK;
    for (int i = t; i < NB; i += 256) hist[i] = 0;
    __syncthreads();
    int rows[EPB], ranks[EPB];
#pragma unroll
    for (int k = 0; k < EPB; ++k) {
        int e = start + t + k * 256;
        if (e < NUM_EDGES) {
            int r = erow[e];
            rows[k]  = r;
            ranks[k] = atomicAdd(&hist[r >> 8], 1);
        } else {
            rows[k] = -1;
        }
    }
    __syncthreads();
    for (int i = t; i < NB; i += 256) {
        int c = hist[i];
        base[i] = c ? atomicAdd(&bcur[i], c) : 0;
    }
    __syncthreads();
#pragma unroll
    for (int k = 0; k < EPB; ++k) {
        int e = start + t + k * 256;
        if (rows[k] >= 0) {
            int r   = rows[k];
            int pos = base[r >> 8] + ranks[k];
            tmp[pos] = make_int2(((r & 255) << 24) | ecol[e], __float_as_int(eval_[e]));
        }
    }
}

// Pass 2: per bucket — count rows, local scan, emit row_ptr, scatter to epack.
// Bucket (~40 KB) is L2-resident for the second read; zero global atomics.
__global__ void k_part2(const int* __restrict__ bbase, const int2* __restrict__ tmp,
                        int2* __restrict__ epack, int* __restrict__ row_ptr) {
    __shared__ int cnt[256];
    __shared__ int sc[256];
    __shared__ int loc[256];
    int b = blockIdx.x, t = threadIdx.x;
    int base_row = b << 8;
    int nrows = min(256, NUM_NODES - base_row);
    int s = bbase[b], end = bbase[b + 1];
    cnt[t] = 0;
    __syncthreads();
    for (int i = s + t; i < end; i += 256)
        atomicAdd(&cnt[((unsigned)tmp[i].x) >> 24], 1);
    __syncthreads();
    int v = cnt[t];
    sc[t] = v;
    __syncthreads();
    for (int off = 1; off < 256; off <<= 1) {
        int add = (t >= off) ? sc[t - off] : 0;
        __syncthreads();
        sc[t] += add;
        __syncthreads();
    }
    int cur = s + sc[t] - v;   // exclusive
    if (t < nrows) row_ptr[base_row + t] = cur;
    loc[t] = cur;
    __syncthreads();
    for (int i = s + t; i < end; i += 256) {
        int2 rec = tmp[i];
        int pos = atomicAdd(&loc[((unsigned)rec.x) >> 24], 1);
        epack[pos] = make_int2(rec.x & 0xFFFFFF, rec.y);
    }
    if (b == 0 && t == 0) row_ptr[NUM_NODES] = NUM_EDGES;
}

// ---------------- SpMM layer 1: h1 = A * x  (wave per row, lane = dim, bf16 gathers) ----

__global__ void k_spmm1(const int* __restrict__ row_ptr, const int2* __restrict__ epack,
                        const unsigned short* __restrict__ xb,
                        unsigned short* __restrict__ h1) {
    int wid  = (blockIdx.x * blockDim.x + threadIdx.x) >> 6;
    int lane = threadIdx.x & 63;
    if (wid >= NUM_NODES) return;
    int s = row_ptr[wid];
    int t = row_ptr[wid + 1];
    float acc0 = 0.f, acc1 = 0.f;
    int e = s;
    for (; e + 4 <= t; e += 4) {
        int2 p0 = epack[e],     p1 = epack[e + 1];
        int2 p2 = epack[e + 2], p3 = epack[e + 3];
        float x0 = bf2f(xb[(size_t)p0.x * EMB + lane]);
        float x1 = bf2f(xb[(size_t)p1.x * EMB + lane]);
        float x2 = bf2f(xb[(size_t)p2.x * EMB + lane]);
        float x3 = bf2f(xb[(size_t)p3.x * EMB + lane]);
        acc0 = fmaf(__int_as_float(p0.y), x0, acc0);
        acc1 = fmaf(__int_as_float(p1.y), x1, acc1);
        acc0 = fmaf(__int_as_float(p2.y), x2, acc0);
        acc1 = fmaf(__int_as_float(p3.y), x3, acc1);
    }
    for (; e < t; ++e) {
        int2 p = epack[e];
        acc0 = fmaf(__int_as_float(p.y), bf2f(xb[(size_t)p.x * EMB + lane]), acc0);
    }
    h1[(size_t)wid * EMB + lane] = f2bf(acc0 + acc1);
}

// ---------------- Fused layer 2 + scoring ----------------
// block = 192 threads = 3 waves: wave0 -> user, wave1 -> pos, wave2 -> neg.
// acc = (x_fp32 + h1 + A*h1)[node] / 3 ; then dot products via wave reduction.

__device__ __forceinline__ const float* node_ptr(int c, const float* __restrict__ uemb,
                                                 const float* __restrict__ iemb) {
    return (c < NUM_USERS) ? (uemb + (size_t)c * EMB)
                           : (iemb + (size_t)(c - NUM_USERS) * EMB);
}

__global__ void k_final(const int* __restrict__ user, const int* __restrict__ pos,
                        const int* __restrict__ neg,
                        const int* __restrict__ row_ptr, const int2* __restrict__ epack,
                        const float* __restrict__ uemb, const float* __restrict__ iemb,
                        const unsigned short* __restrict__ h1, float* __restrict__ out) {
    __shared__ float lds[3 * EMB];
    int b    = blockIdx.x;
    int w    = threadIdx.x >> 6;
    int lane = threadIdx.x & 63;

    int node;
    if (w == 0)      node = user[b];
    else if (w == 1) node = NUM_USERS + pos[b];
    else             node = NUM_USERS + neg[b];

    const float* xbp = node_ptr(node, uemb, iemb);
    float acc = xbp[lane] + bf2f(h1[(size_t)node * EMB + lane]);

    int s = row_ptr[node];
    int t = row_ptr[node + 1];
    int e = s;
    for (; e + 2 <= t; e += 2) {
        int2 p0 = epack[e], p1 = epack[e + 1];
        float y0 = bf2f(h1[(size_t)p0.x * EMB + lane]);
        float y1 = bf2f(h1[(size_t)p1.x * EMB + lane]);
        acc = fmaf(__int_as_float(p0.y), y0, acc);
        acc = fmaf(__int_as_float(p1.y), y1, acc);
    }
    for (; e < t; ++e) {
        int2 p = epack[e];
        acc = fmaf(__int_as_float(p.y), bf2f(h1[(size_t)p.x * EMB + lane]), acc);
    }

    acc = acc / 3.0f;
    lds[w * EMB + lane] = acc;
    __syncthreads();

    if (w < 2) {
        float prod = lds[lane] * lds[(w + 1) * EMB + lane];
        for (int off = 32; off; off >>= 1) prod += __shfl_xor(prod, off, 64);
        if (lane == 0) out[w * BATCH + b] = prod;
    }
}

// ---------------- launch ----------------

extern "C" void kernel_launch(void* const* d_in, const int* in_sizes, int n_in,
                              void* d_out, int out_size, void* d_ws, size_t ws_size,
                              hipStream_t stream) {
    const int*   user  = (const int*)d_in[0];
    const int*   pos   = (const int*)d_in[1];
    const int*   neg   = (const int*)d_in[2];
    const int*   erow  = (const int*)d_in[3];
    const int*   ecol  = (const int*)d_in[4];
    const float* eval_ = (const float*)d_in[5];
    const float* uemb  = (const float*)d_in[6];
    const float* iemb  = (const float*)d_in[7];
    float* out = (float*)d_out;

    char* ws = (char*)d_ws;
    // layout (bytes):
    //   xb      : 0          .. +25,600,000  (200000*64 bf16)
    //   h1      : 25,600,000 .. +25,600,000  (bf16)
    //   row_ptr : 51,200,000 .. +800,064     (200001 ints)
    //   bcnt    : 52,000,064 .. +4,096
    //   bbase   : 52,004,160 .. +4,096       (783 ints)
    //   bcur    : 52,008,256 .. +4,096
    //   epack   : 52,012,352 .. +32,000,000
    //   tmp     : 84,012,352 .. +32,000,000  (end 116,012,352; ws proven >= 116.8 MB in R4)
    unsigned short* xb    = (unsigned short*)(ws);
    unsigned short* h1    = (unsigned short*)(ws + 25600000);
    int*  row_ptr = (int*)(ws + 51200000);
    int*  bcnt    = (int*)(ws + 52000064);
    int*  bbase   = (int*)(ws + 52004160);
    int*  bcur    = (int*)(ws + 52008256);
    int2* epack   = (int2*)(ws + 52012352);
    int2* tmp     = (int2*)(ws + 84012352);

    hipMemsetAsync(bcnt, 0, NB * sizeof(int), stream);

    k_cvt<<<((NUM_NODES * EMB) / 8 + 255) / 256, 256, 0, stream>>>(uemb, iemb, xb);

    int nblk = (NUM_EDGES + CHUNK - 1) / CHUNK;  // 489
    k_bhist<<<nblk, 256, 0, stream>>>(erow, bcnt);
    k_bscan<<<1, 1024, 0, stream>>>(bcnt, bbase, bcur);

    k_part1<<<nblk, 256, 0, stream>>>(erow, ecol, eval_, bcur, tmp);
    k_part2<<<NB, 256, 0, stream>>>(bbase, tmp, epack, row_ptr);

    k_spmm1<<<(NUM_NODES * 64 + 255) / 256, 256, 0, stream>>>(row_ptr, epack, xb, h1);

    k_final<<<BATCH, 192, 0, stream>>>(user, pos, neg, row_ptr, epack,
                                       uemb, iemb, h1, out);
}

// Round 6
// 398.959 us; speedup vs baseline: 1.8694x; 1.1539x over previous
//
#include <hip/hip_runtime.h>
#include <cstdint>
#include <cstddef>

#define NUM_USERS 100000
#define NUM_ITEMS 100000
#define NUM_NODES 200000
#define NUM_EDGES 4000000
#define BATCH     4096
#define EMB       64

#define NB    782          // ceil(NUM_NODES / 256) buckets (bucket = row >> 8)
#define CHUNK 8192         // edges per block in k_bhist / k_part1
#define EPB   32           // CHUNK / 256 edges per thread

// ---------------- bf16 helpers (round-to-nearest-even) ----------------

__device__ __forceinline__ unsigned short f2bf(float f) {
    unsigned u = __float_as_uint(f);
    u = (u + 0x7FFFu + ((u >> 16) & 1u)) >> 16;
    return (unsigned short)u;
}
__device__ __forceinline__ float bf2f(unsigned short b) {
    return __uint_as_float(((unsigned)b) << 16);
}

// ---------------- convert fp32 embeddings -> bf16 table (user ‖ item) ----------------

__global__ void k_cvt(const float* __restrict__ uemb, const float* __restrict__ iemb,
                      unsigned short* __restrict__ xb) {
    int i = blockIdx.x * blockDim.x + threadIdx.x;           // 8 elems / thread
    const int TOT8 = (NUM_NODES * EMB) / 8;                  // 1.6M
    if (i >= TOT8) return;
    size_t off = (size_t)i * 8;
    const size_t UELEMS = (size_t)NUM_USERS * EMB;           // divisible by 8
    const float* src = (off < UELEMS) ? (uemb + off) : (iemb + (off - UELEMS));
    float4 f0 = ((const float4*)src)[0];
    float4 f1 = ((const float4*)src)[1];
    ushort4 o0 = make_ushort4(f2bf(f0.x), f2bf(f0.y), f2bf(f0.z), f2bf(f0.w));
    ushort4 o1 = make_ushort4(f2bf(f1.x), f2bf(f1.y), f2bf(f1.z), f2bf(f1.w));
    ((ushort4*)(xb + off))[0] = o0;
    ((ushort4*)(xb + off))[1] = o1;
}

// ---------------- bucket histogram (782 buckets, LDS-aggregated) ----------------

__global__ void k_bhist(const int* __restrict__ erow, int* __restrict__ bcnt) {
    __shared__ int h[NB];
    int t = threadIdx.x;
    int start = blockIdx.x * CHUNK;
    for (int i = t; i < NB; i += 256) h[i] = 0;
    __syncthreads();
#pragma unroll
    for (int k = 0; k < EPB; ++k) {
        int e = start + t + k * 256;
        if (e < NUM_EDGES) atomicAdd(&h[erow[e] >> 8], 1);
    }
    __syncthreads();
    for (int i = t; i < NB; i += 256) {
        int c = h[i];
        if (c) atomicAdd(&bcnt[i], c);
    }
}

// exclusive scan over 782 bucket counts -> bbase[0..NB], init bcur
__global__ void k_bscan(const int* __restrict__ bcnt, int* __restrict__ bbase,
                        int* __restrict__ bcur) {
    __shared__ int lds[1024];
    int t = threadIdx.x;
    int v = (t < NB) ? bcnt[t] : 0;
    lds[t] = v;
    __syncthreads();
    for (int off = 1; off < 1024; off <<= 1) {
        int add = (t >= off) ? lds[t - off] : 0;
        __syncthreads();
        lds[t] += add;
        __syncthreads();
    }
    int ex = lds[t] - v;
    if (t < NB) { bbase[t] = ex; bcur[t] = ex; }
    if (t == NB - 1) bbase[NB] = lds[t];
}

// ---------------- two-level partition ----------------

__global__ void k_part1(const int* __restrict__ erow, const int* __restrict__ ecol,
                        const float* __restrict__ eval_, int* __restrict__ bcur,
                        int2* __restrict__ tmp) {
    __shared__ int hist[NB];
    __shared__ int base[NB];
    int t = threadIdx.x;
    int start = blockIdx.x * CHUNK;
    for (int i = t; i < NB; i += 256) hist[i] = 0;
    __syncthreads();
    int rows[EPB], ranks[EPB];
#pragma unroll
    for (int k = 0; k < EPB; ++k) {
        int e = start + t + k * 256;
        if (e < NUM_EDGES) {
            int r = erow[e];
            rows[k]  = r;
            ranks[k] = atomicAdd(&hist[r >> 8], 1);
        } else {
            rows[k] = -1;
        }
    }
    __syncthreads();
    for (int i = t; i < NB; i += 256) {
        int c = hist[i];
        base[i] = c ? atomicAdd(&bcur[i], c) : 0;
    }
    __syncthreads();
#pragma unroll
    for (int k = 0; k < EPB; ++k) {
        int e = start + t + k * 256;
        if (rows[k] >= 0) {
            int r   = rows[k];
            int pos = base[r >> 8] + ranks[k];
            tmp[pos] = make_int2(((r & 255) << 24) | ecol[e], __float_as_int(eval_[e]));
        }
    }
}

__global__ void k_part2(const int* __restrict__ bbase, const int2* __restrict__ tmp,
                        int2* __restrict__ epack, int* __restrict__ row_ptr) {
    __shared__ int cnt[256];
    __shared__ int sc[256];
    __shared__ int loc[256];
    int b = blockIdx.x, t = threadIdx.x;
    int base_row = b << 8;
    int nrows = min(256, NUM_NODES - base_row);
    int s = bbase[b], end = bbase[b + 1];
    cnt[t] = 0;
    __syncthreads();
    for (int i = s + t; i < end; i += 256)
        atomicAdd(&cnt[((unsigned)tmp[i].x) >> 24], 1);
    __syncthreads();
    int v = cnt[t];
    sc[t] = v;
    __syncthreads();
    for (int off = 1; off < 256; off <<= 1) {
        int add = (t >= off) ? sc[t - off] : 0;
        __syncthreads();
        sc[t] += add;
        __syncthreads();
    }
    int cur = s + sc[t] - v;   // exclusive
    if (t < nrows) row_ptr[base_row + t] = cur;
    loc[t] = cur;
    __syncthreads();
    for (int i = s + t; i < end; i += 256) {
        int2 rec = tmp[i];
        int pos = atomicAdd(&loc[((unsigned)rec.x) >> 24], 1);
        epack[pos] = make_int2(rec.x & 0xFFFFFF, rec.y);
    }
    if (b == 0 && t == 0) row_ptr[NUM_NODES] = NUM_EDGES;
}

// ---------------- SpMM layer 1: h1 = A * x ----------------
// Wave = 1 row. Four 16-lane edge-groups: group g handles edge e+g, lane
// holds dim-quad (lane&15)*4 via one ushort4 (8 B) load -> one wave-level
// VMEM issue covers 4 edges (512 B) instead of 1 (128 B). Cross-group sum
// via 2 shfl_xor at the end.

__global__ void k_spmm1(const int* __restrict__ row_ptr, const int2* __restrict__ epack,
                        const unsigned short* __restrict__ xb,
                        unsigned short* __restrict__ h1) {
    int wid  = (blockIdx.x * blockDim.x + threadIdx.x) >> 6;
    int lane = threadIdx.x & 63;
    if (wid >= NUM_NODES) return;
    int g = lane >> 4;
    int q = (lane & 15) * 4;
    int s = row_ptr[wid];
    int t = row_ptr[wid + 1];
    float a0 = 0.f, a1 = 0.f, a2 = 0.f, a3 = 0.f;
    for (int e = s; e < t; e += 8) {
        int eA = e + g, eB = e + 4 + g;
        int2 pA = epack[eA < t ? eA : s];
        int2 pB = epack[eB < t ? eB : s];
        float vA = (eA < t) ? __int_as_float(pA.y) : 0.f;
        float vB = (eB < t) ? __int_as_float(pB.y) : 0.f;
        ushort4 xA = *(const ushort4*)(xb + (size_t)pA.x * EMB + q);
        ushort4 xB = *(const ushort4*)(xb + (size_t)pB.x * EMB + q);
        a0 = fmaf(vA, bf2f(xA.x), a0); a1 = fmaf(vA, bf2f(xA.y), a1);
        a2 = fmaf(vA, bf2f(xA.z), a2); a3 = fmaf(vA, bf2f(xA.w), a3);
        a0 = fmaf(vB, bf2f(xB.x), a0); a1 = fmaf(vB, bf2f(xB.y), a1);
        a2 = fmaf(vB, bf2f(xB.z), a2); a3 = fmaf(vB, bf2f(xB.w), a3);
    }
    a0 += __shfl_xor(a0, 16, 64); a1 += __shfl_xor(a1, 16, 64);
    a2 += __shfl_xor(a2, 16, 64); a3 += __shfl_xor(a3, 16, 64);
    a0 += __shfl_xor(a0, 32, 64); a1 += __shfl_xor(a1, 32, 64);
    a2 += __shfl_xor(a2, 32, 64); a3 += __shfl_xor(a3, 32, 64);
    if (lane < 16) {
        ushort4 o = make_ushort4(f2bf(a0), f2bf(a1), f2bf(a2), f2bf(a3));
        *(ushort4*)(h1 + (size_t)wid * EMB + q) = o;
    }
}

// ---------------- Fused layer 2 + scoring (same 4-edge-group gather) ----------------

__device__ __forceinline__ const float* node_ptr(int c, const float* __restrict__ uemb,
                                                 const float* __restrict__ iemb) {
    return (c < NUM_USERS) ? (uemb + (size_t)c * EMB)
                           : (iemb + (size_t)(c - NUM_USERS) * EMB);
}

__global__ void k_final(const int* __restrict__ user, const int* __restrict__ pos,
                        const int* __restrict__ neg,
                        const int* __restrict__ row_ptr, const int2* __restrict__ epack,
                        const float* __restrict__ uemb, const float* __restrict__ iemb,
                        const unsigned short* __restrict__ h1, float* __restrict__ out) {
    __shared__ float lds[3 * EMB];
    int b    = blockIdx.x;
    int w    = threadIdx.x >> 6;
    int lane = threadIdx.x & 63;
    int g = lane >> 4;
    int q = (lane & 15) * 4;

    int node;
    if (w == 0)      node = user[b];
    else if (w == 1) node = NUM_USERS + pos[b];
    else             node = NUM_USERS + neg[b];

    int s = row_ptr[node];
    int t = row_ptr[node + 1];
    float a0 = 0.f, a1 = 0.f, a2 = 0.f, a3 = 0.f;
    for (int e = s; e < t; e += 8) {
        int eA = e + g, eB = e + 4 + g;
        int2 pA = epack[eA < t ? eA : s];
        int2 pB = epack[eB < t ? eB : s];
        float vA = (eA < t) ? __int_as_float(pA.y) : 0.f;
        float vB = (eB < t) ? __int_as_float(pB.y) : 0.f;
        ushort4 yA = *(const ushort4*)(h1 + (size_t)pA.x * EMB + q);
        ushort4 yB = *(const ushort4*)(h1 + (size_t)pB.x * EMB + q);
        a0 = fmaf(vA, bf2f(yA.x), a0); a1 = fmaf(vA, bf2f(yA.y), a1);
        a2 = fmaf(vA, bf2f(yA.z), a2); a3 = fmaf(vA, bf2f(yA.w), a3);
        a0 = fmaf(vB, bf2f(yB.x), a0); a1 = fmaf(vB, bf2f(yB.y), a1);
        a2 = fmaf(vB, bf2f(yB.z), a2); a3 = fmaf(vB, bf2f(yB.w), a3);
    }
    a0 += __shfl_xor(a0, 16, 64); a1 += __shfl_xor(a1, 16, 64);
    a2 += __shfl_xor(a2, 16, 64); a3 += __shfl_xor(a3, 16, 64);
    a0 += __shfl_xor(a0, 32, 64); a1 += __shfl_xor(a1, 32, 64);
    a2 += __shfl_xor(a2, 32, 64); a3 += __shfl_xor(a3, 32, 64);

    if (lane < 16) {
        const float* xbp = node_ptr(node, uemb, iemb) + q;
        float4  xd = *(const float4*)xbp;
        ushort4 hn = *(const ushort4*)(h1 + (size_t)node * EMB + q);
        a0 = (a0 + xd.x + bf2f(hn.x)) / 3.0f;
        a1 = (a1 + xd.y + bf2f(hn.y)) / 3.0f;
        a2 = (a2 + xd.z + bf2f(hn.z)) / 3.0f;
        a3 = (a3 + xd.w + bf2f(hn.w)) / 3.0f;
        *(float4*)(lds + w * EMB + q) = make_float4(a0, a1, a2, a3);
    }
    __syncthreads();

    if (w < 2) {
        float prod = lds[lane] * lds[(w + 1) * EMB + lane];
        for (int off = 32; off; off >>= 1) prod += __shfl_xor(prod, off, 64);
        if (lane == 0) out[w * BATCH + b] = prod;
    }
}

// ---------------- launch ----------------

extern "C" void kernel_launch(void* const* d_in, const int* in_sizes, int n_in,
                              void* d_out, int out_size, void* d_ws, size_t ws_size,
                              hipStream_t stream) {
    const int*   user  = (const int*)d_in[0];
    const int*   pos   = (const int*)d_in[1];
    const int*   neg   = (const int*)d_in[2];
    const int*   erow  = (const int*)d_in[3];
    const int*   ecol  = (const int*)d_in[4];
    const float* eval_ = (const float*)d_in[5];
    const float* uemb  = (const float*)d_in[6];
    const float* iemb  = (const float*)d_in[7];
    float* out = (float*)d_out;

    char* ws = (char*)d_ws;
    // layout (bytes):
    //   xb      : 0          .. +25,600,000  (200000*64 bf16)
    //   h1      : 25,600,000 .. +25,600,000  (bf16)
    //   row_ptr : 51,200,000 .. +800,064     (200001 ints)
    //   bcnt    : 52,000,064 .. +4,096
    //   bbase   : 52,004,160 .. +4,096       (783 ints)
    //   bcur    : 52,008,256 .. +4,096
    //   epack   : 52,012,352 .. +32,000,000
    //   tmp     : 84,012,352 .. +32,000,000  (end 116,012,352)
    unsigned short* xb = (unsigned short*)(ws);
    unsigned short* h1 = (unsigned short*)(ws + 25600000);
    int*  row_ptr = (int*)(ws + 51200000);
    int*  bcnt    = (int*)(ws + 52000064);
    int*  bbase   = (int*)(ws + 52004160);
    int*  bcur    = (int*)(ws + 52008256);
    int2* epack   = (int2*)(ws + 52012352);
    int2* tmp     = (int2*)(ws + 84012352);

    hipMemsetAsync(bcnt, 0, NB * sizeof(int), stream);

    k_cvt<<<((NUM_NODES * EMB) / 8 + 255) / 256, 256, 0, stream>>>(uemb, iemb, xb);

    int nblk = (NUM_EDGES + CHUNK - 1) / CHUNK;  // 489
    k_bhist<<<nblk, 256, 0, stream>>>(erow, bcnt);
    k_bscan<<<1, 1024, 0, stream>>>(bcnt, bbase, bcur);

    k_part1<<<nblk, 256, 0, stream>>>(erow, ecol, eval_, bcur, tmp);
    k_part2<<<NB, 256, 0, stream>>>(bbase, tmp, epack, row_ptr);

    k_spmm1<<<(NUM_NODES * 64 + 255) / 256, 256, 0, stream>>>(row_ptr, epack, xb, h1);

    k_final<<<BATCH, 192, 0, stream>>>(user, pos, neg, row_ptr, epack,
                                       uemb, iemb, h1, out);
}